// Round 8
// baseline (18.095 us; speedup 1.0000x reference)
//
#include <hip/hip_runtime.h>

namespace {
constexpr int Bn = 64;
constexpr int Ln = 512;
constexpr int Hn = 768;
constexpr int Dn = 16;
constexpr float NEGV = -900000.0f;
}

// ---------------------------------------------------------------------------
// R5 structure + R7's cheap wins. 256 threads = 4 waves; wave w owns rows
// {w, w+4, ...} (NIT=8 query / 7 doc).
//  Phase 1: load 3 float4/lane per row (lane+64j covers all 768 cols), dot
//           with W, 6-step shfl_xor reduce, lane0 -> score_sh[s]; rows stay
//           in registers.                                    [barrier 1]
//  Softmax: redundant in every wave (width-32, both halves) from score_sh;
//           no barrier after. alpha[s] via in-wave __shfl.
//  Phase 2: pure register FMA into per-wave acc; partials to 12 KB LDS.
//                                                            [barrier 2]
//  Epilogue: threads 0..191 sum 4 partials, store float4 (once — no
//           redundant wave stores); query broadcasts to 16 slots.
// Every hidden_states byte read exactly once, as dwordx4.
// ---------------------------------------------------------------------------
__global__ __launch_bounds__(256) void k_fused(
    const float* __restrict__ hs,
    const float* __restrict__ Wd, const float* __restrict__ bd,
    const float* __restrict__ Wq, const float* __restrict__ bq,
    const int* __restrict__ qlen, const int* __restrict__ slens,
    float* __restrict__ out_doc, float* __restrict__ out_q)
{
    __shared__ float score_sh[32];
    __shared__ float4 pool4[4][192];          // 12 KB

    const int t = threadIdx.x;
    const int wave = t >> 6;
    const int lane = t & 63;
    const int bid = blockIdx.x;

    const float* rowbase;
    const float* W;
    float bias;
    int len;
    int b, d = 0;
    const bool isq = (bid < Bn);

    if (isq) {
        b = bid;
        len = qlen[b];                                   // 8..32
        W = Wq; bias = bq[0];
        rowbase = hs + ((size_t)b * Ln + 1) * Hn;
    } else {
        const int id = bid - Bn;
        b = id >> 4;
        d = id & 15;
        const int sv = slens[b * Dn + (lane & 15)];      // lanes hold slens[b,:]
        len = __shfl(sv, d, 64);                         // this doc's len
        if (len == 0) {                                  // ~36% of doc blocks
            if (t < 192) {
                float4* o4 = reinterpret_cast<float4*>(out_doc + ((size_t)b * Dn + d) * Hn);
                o4[t] = make_float4(0.f, 0.f, 0.f, 0.f);
            }
            return;
        }
        int pref = 0;
#pragma unroll
        for (int k = 0; k < Dn; ++k)
            pref += (k < d) ? __shfl(sv, k, 64) : 0;
        const int base = qlen[b] + 2 + pref;             // max valid idx 481 < 512
        W = Wd; bias = bd[0];
        rowbase = hs + ((size_t)b * Ln + base) * Hn;
    }

    float4 wv[3];
#pragma unroll
    for (int j = 0; j < 3; ++j)
        wv[j] = *reinterpret_cast<const float4*>(W + (lane + 64 * j) * 4);

    // ---- phase 1: load rows once, score, keep rows in registers ----
    float4 c[8][3];
#pragma unroll
    for (int it = 0; it < 8; ++it) {
        const int s = wave + 4 * it;                     // wave-uniform predicate
        if (s < len) {                                   // len<=32 -> it=8 only for query
            const float* r = rowbase + s * Hn;
#pragma unroll
            for (int j = 0; j < 3; ++j)
                c[it][j] = *reinterpret_cast<const float4*>(r + (lane + 64 * j) * 4);
            float p = c[it][0].x * wv[0].x + c[it][0].y * wv[0].y
                    + c[it][0].z * wv[0].z + c[it][0].w * wv[0].w
                    + c[it][1].x * wv[1].x + c[it][1].y * wv[1].y
                    + c[it][1].z * wv[1].z + c[it][1].w * wv[1].w
                    + c[it][2].x * wv[2].x + c[it][2].y * wv[2].y
                    + c[it][2].z * wv[2].z + c[it][2].w * wv[2].w;
#pragma unroll
            for (int off = 32; off; off >>= 1) p += __shfl_xor(p, off);
            if (lane == 0) score_sh[s] = p;
        }
    }
    __syncthreads();                                     // barrier 1

    // ---- softmax, redundant in every wave -> no barrier after ----
    const int si = lane & 31;
    const float raw = (si < len) ? (score_sh[si] + bias) : NEGV;
    float mx = raw;
#pragma unroll
    for (int off = 16; off; off >>= 1) mx = fmaxf(mx, __shfl_xor(mx, off, 32));
    const float e = __expf(raw - mx);
    float den = e;
#pragma unroll
    for (int off = 16; off; off >>= 1) den += __shfl_xor(den, off, 32);
    const float alpha = (si < len) ? (e / den) : 0.f;    // lane i holds alpha[i&31]

    // ---- phase 2: pure register FMA per wave ----
    float4 acc[3];
#pragma unroll
    for (int j = 0; j < 3; ++j) acc[j] = make_float4(0.f, 0.f, 0.f, 0.f);
#pragma unroll
    for (int it = 0; it < 8; ++it) {
        const int s = wave + 4 * it;
        if (s < len) {
            const float a = __shfl(alpha, s, 64);        // s < 32
            acc[0].x += a * c[it][0].x; acc[0].y += a * c[it][0].y;
            acc[0].z += a * c[it][0].z; acc[0].w += a * c[it][0].w;
            acc[1].x += a * c[it][1].x; acc[1].y += a * c[it][1].y;
            acc[1].z += a * c[it][1].z; acc[1].w += a * c[it][1].w;
            acc[2].x += a * c[it][2].x; acc[2].y += a * c[it][2].y;
            acc[2].z += a * c[it][2].z; acc[2].w += a * c[it][2].w;
        }
    }

    // ---- cross-wave combine ----
#pragma unroll
    for (int j = 0; j < 3; ++j) pool4[wave][lane + 64 * j] = acc[j];
    __syncthreads();                                     // barrier 2

    if (t < 192) {
        float4 r = pool4[0][t];
#pragma unroll
        for (int w = 1; w < 4; ++w) {
            const float4 s = pool4[w][t];
            r.x += s.x; r.y += s.y; r.z += s.z; r.w += s.w;
        }
        if (isq) {
            for (int dd = 0; dd < Dn; ++dd) {
                float4* o4 = reinterpret_cast<float4*>(out_q + ((size_t)b * Dn + dd) * Hn);
                o4[t] = r;
            }
        } else {
            float4* o4 = reinterpret_cast<float4*>(out_doc + ((size_t)b * Dn + d) * Hn);
            o4[t] = r;
        }
    }
}

extern "C" void kernel_launch(void* const* d_in, const int* in_sizes, int n_in,
                              void* d_out, int out_size, void* d_ws, size_t ws_size,
                              hipStream_t stream)
{
    const float* hs    = (const float*)d_in[0];   // (B,L,H) f32
    const float* Wd    = (const float*)d_in[1];   // (H,1)
    const float* bd    = (const float*)d_in[2];   // (1,)
    const float* Wq    = (const float*)d_in[3];   // (H,1)
    const float* bq    = (const float*)d_in[4];   // (1,)
    const int*   qlen  = (const int*)d_in[5];     // (B,)
    const int*   slens = (const int*)d_in[6];     // (B,D)

    float* out_doc = (float*)d_out;                       // (B,D,H) doc_pooled
    float* out_q   = out_doc + (size_t)Bn * Dn * Hn;      // (B,D,H) q_bcast

    k_fused<<<Bn + Bn * Dn, 256, 0, stream>>>(hs, Wd, bd, Wq, bq,
                                              qlen, slens, out_doc, out_q);
}

// Round 9
// 17.752 us; speedup vs baseline: 1.0193x; 1.0193x over previous
//
#include <hip/hip_runtime.h>

namespace {
constexpr int Bn = 64;
constexpr int Ln = 512;
constexpr int Hn = 768;
constexpr int Dn = 16;
constexpr int Qn = 32;
constexpr float NEGV = -900000.0f;
}

// ---------------------------------------------------------------------------
// R5 structure (best measured: 16.4 us), with critical-path head/tail fixes:
//  - all long-latency setup loads (slens, qlen, W weights, bias) issued
//    together at kernel start, before the shfl prefix chain
//  - float4 epilogue / zero-fill by threads 0..191 (no scalar / redundant
//    stores)
// Core (unchanged from R5): 256 threads = 4 waves; wave w owns rows
// {w, w+4, ...}; phase 1 loads each row once (3 float4/lane), dots with W,
// 6-step shfl_xor reduce -> score_sh; wave 0 does the masked width-32
// softmax; phase 2 is pure register FMA on the kept rows; partials combine
// through 12 KB LDS. Every hidden_states byte read exactly once, as dwordx4.
// ---------------------------------------------------------------------------
template<int NIT>
__device__ __forceinline__ void pool_span(
    const float* __restrict__ rowbase, const float4 wv[3], float bias, int len,
    float* __restrict__ score_sh, float4 (*pool4)[192],
    int t, int wave, int lane, float4 out4[3])
{
    // phase 1: load rows once, score, keep rows in registers
    float4 c[NIT][3];
#pragma unroll
    for (int it = 0; it < NIT; ++it) {
        const int s = wave + 4 * it;                  // wave-uniform predicate
        if (s < len) {
            const float* r = rowbase + s * Hn;
#pragma unroll
            for (int j = 0; j < 3; ++j)
                c[it][j] = *reinterpret_cast<const float4*>(r + (lane + 64 * j) * 4);
            float p = c[it][0].x * wv[0].x + c[it][0].y * wv[0].y
                    + c[it][0].z * wv[0].z + c[it][0].w * wv[0].w
                    + c[it][1].x * wv[1].x + c[it][1].y * wv[1].y
                    + c[it][1].z * wv[1].z + c[it][1].w * wv[1].w
                    + c[it][2].x * wv[2].x + c[it][2].y * wv[2].y
                    + c[it][2].z * wv[2].z + c[it][2].w * wv[2].w;
#pragma unroll
            for (int off = 32; off; off >>= 1) p += __shfl_down(p, off);
            if (lane == 0) score_sh[s] = p;
        }
    }
    __syncthreads();                                  // barrier 1: scores ready

    // masked softmax in 32 lanes of wave 0; alpha (0 for masked) -> score_sh
    if (t < Qn) {
        const float raw = (t < len) ? (score_sh[t] + bias) : NEGV;
        float m = raw;
#pragma unroll
        for (int off = 16; off; off >>= 1) m = fmaxf(m, __shfl_xor(m, off, 32));
        const float e = expf(raw - m);
        float den = e;
#pragma unroll
        for (int off = 16; off; off >>= 1) den += __shfl_xor(den, off, 32);
        score_sh[t] = (t < len) ? (e / den) : 0.f;
    }
    __syncthreads();                                  // barrier 2: alpha ready

    // phase 2: pure register FMA per wave (alpha via LDS broadcast)
    float4 acc[3];
#pragma unroll
    for (int j = 0; j < 3; ++j) acc[j] = make_float4(0.f, 0.f, 0.f, 0.f);
#pragma unroll
    for (int it = 0; it < NIT; ++it) {
        const int s = wave + 4 * it;
        if (s < len) {
            const float a = score_sh[s];
#pragma unroll
            for (int j = 0; j < 3; ++j) {
                acc[j].x += a * c[it][j].x;
                acc[j].y += a * c[it][j].y;
                acc[j].z += a * c[it][j].z;
                acc[j].w += a * c[it][j].w;
            }
        }
    }

    // cross-wave combine
#pragma unroll
    for (int j = 0; j < 3; ++j) pool4[wave][lane + 64 * j] = acc[j];
    __syncthreads();                                  // barrier 3: partials ready

    if (t < 192) {
        float4 r = pool4[0][t];
#pragma unroll
        for (int w = 1; w < 4; ++w) {
            const float4 s = pool4[w][t];
            r.x += s.x; r.y += s.y; r.z += s.z; r.w += s.w;
        }
        out4[0] = r;
    }
}

__global__ __launch_bounds__(256) void k_fused(
    const float* __restrict__ hs,
    const float* __restrict__ Wd, const float* __restrict__ bd,
    const float* __restrict__ Wq, const float* __restrict__ bq,
    const int* __restrict__ qlen, const int* __restrict__ slens,
    float* __restrict__ out_doc, float* __restrict__ out_q)
{
    __shared__ float score_sh[Qn];
    __shared__ float4 pool4[4][192];      // 12 KB

    const int t = threadIdx.x;
    const int wave = t >> 6;
    const int lane = t & 63;
    const int bid = blockIdx.x;
    const bool isq = (bid < Bn);

    // ---- issue ALL long-latency setup loads together, before any shfl ----
    int b, d = 0;
    const float* W;
    if (isq) { b = bid;              W = Wq; }
    else     { const int id = bid - Bn; b = id >> 4; d = id & 15; W = Wd; }

    const int sv  = isq ? 0 : slens[b * Dn + (lane & 15)];  // in flight
    const int ql  = qlen[b];                                // in flight
    const float bias = isq ? bq[0] : bd[0];                 // in flight
    float4 wv[3];
#pragma unroll
    for (int j = 0; j < 3; ++j)
        wv[j] = *reinterpret_cast<const float4*>(W + (lane + 64 * j) * 4);

    if (isq) {
        // ------------------------- query block -------------------------
        const float* bp = hs + ((size_t)b * Ln + 1) * Hn;
        float4 o4[1];
        pool_span<8>(bp, wv, bias, ql, score_sh, pool4, t, wave, lane, o4);
        if (t < 192) {
            for (int dd = 0; dd < Dn; ++dd) {
                float4* o = reinterpret_cast<float4*>(out_q + ((size_t)b * Dn + dd) * Hn);
                o[t] = o4[0];
            }
        }
    } else {
        // -------------------------- doc block --------------------------
        const int sl = __shfl(sv, d, 64);                   // this doc's len
        float4* o = reinterpret_cast<float4*>(out_doc + ((size_t)b * Dn + d) * Hn);
        if (sl == 0) {                                      // ~36% of doc blocks
            if (t < 192) o[t] = make_float4(0.f, 0.f, 0.f, 0.f);
            return;
        }
        int pref = 0;
#pragma unroll
        for (int k = 0; k < Dn; ++k)
            pref += (k < d) ? __shfl(sv, k, 64) : 0;
        const int base = ql + 2 + pref;                     // max valid idx 481 < 512
        const float* bp = hs + ((size_t)b * Ln + base) * Hn;
        float4 o4[1];
        pool_span<7>(bp, wv, bias, sl, score_sh, pool4, t, wave, lane, o4);
        if (t < 192) o[t] = o4[0];
    }
}

extern "C" void kernel_launch(void* const* d_in, const int* in_sizes, int n_in,
                              void* d_out, int out_size, void* d_ws, size_t ws_size,
                              hipStream_t stream)
{
    const float* hs    = (const float*)d_in[0];   // (B,L,H) f32
    const float* Wd    = (const float*)d_in[1];   // (H,1)
    const float* bd    = (const float*)d_in[2];   // (1,)
    const float* Wq    = (const float*)d_in[3];   // (H,1)
    const float* bq    = (const float*)d_in[4];   // (1,)
    const int*   qlen  = (const int*)d_in[5];     // (B,)
    const int*   slens = (const int*)d_in[6];     // (B,D)

    float* out_doc = (float*)d_out;                       // (B,D,H) doc_pooled
    float* out_q   = out_doc + (size_t)Bn * Dn * Hn;      // (B,D,H) q_bcast

    k_fused<<<Bn + Bn * Dn, 256, 0, stream>>>(hs, Wd, bd, Wq, bq,
                                              qlen, slens, out_doc, out_q);
}